// Round 7
// baseline (165.353 us; speedup 1.0000x reference)
//
#include <hip/hip_runtime.h>

#define BB 8
#define NN 4096
#define TPB 256
#define NCB 16           // column strips of 256 cols
#define SC 256           // cols per strip
#define NRB 8            // row blocks
#define RR 512           // rows per block
#define TSTEPS (RR / 16) // 32
#define NDSLAB (NRB * 4) // deg slabs: (rb, wave)

typedef float f32x4 __attribute__((ext_vector_type(4)));

// ws layout (floats):
//   neighp: [NCB*BB*NN*3]    offset 0        (1572864)  (atomic: [BB*NN*3])
//   degp:   [NDSLAB*BB*NN]   offset 1572864  (1048576)  (atomic: [BB*NN])
// partial-mode total ~10.5 MB

__global__ __launch_bounds__(256) void k_init(float* __restrict__ neighp,
                                              float* __restrict__ degp,
                                              float* __restrict__ out,
                                              int atomic_mode) {
    int i = blockIdx.x * 256 + threadIdx.x;
    if (atomic_mode) {
        if (i < BB * NN * 3) neighp[i] = 0.0f;
        if (i < BB * NN) degp[i] = 0.0f;
    }
    if (i == 0) out[0] = 0.0f;
}

__global__ __launch_bounds__(TPB, 3) void k_main(const float* __restrict__ A,
                                                 const float* __restrict__ p1,
                                                 const float* __restrict__ p2,
                                                 float* __restrict__ neighp,
                                                 float* __restrict__ degp,
                                                 int atomic_mode) {
    const int lane = threadIdx.x & 63;
    const int w    = threadIdx.x >> 6;   // wave 0..3
    const int rs   = lane >> 4;          // row sub-slot 0..3
    const int cq   = lane & 15;          // col-16-group 0..15

    int bid = blockIdx.x;
    const int cb = bid & (NCB - 1); bid >>= 4;
    const int rb = bid & (NRB - 1); bid >>= 3;
    const int b  = bid;                  // 0..7

    const int col  = cb * SC + cq * 16;  // lane's 16 fixed columns
    const int row0 = rb * RR + w * 4 + rs;

    // q for the 16 fixed columns, computed in-register from preds (48 floats)
    const size_t qbase = ((size_t)b * NN + col) * 3;
    float qf[48];
#pragma unroll
    for (int k = 0; k < 12; ++k) {
        const f32x4 t1 = *(const f32x4*)(p1 + qbase + 4 * k);
        const f32x4 t2 = *(const f32x4*)(p2 + qbase + 4 * k);
        qf[4 * k + 0] = t2[0] - t1[0];
        qf[4 * k + 1] = t2[1] - t1[1];
        qf[4 * k + 2] = t2[2] - t1[2];
        qf[4 * k + 3] = t2[3] - t1[3];
    }

    const float* Ap = A + (size_t)b * NN * NN + (size_t)row0 * NN + col;

    float dg[16];
#pragma unroll
    for (int c = 0; c < 16; ++c) dg[c] = 0.0f;

    float* npbase = atomic_mode ? (neighp + (size_t)b * NN * 3)
                                : (neighp + (size_t)(cb * BB + b) * NN * 3);

#pragma unroll 2
    for (int t = 0; t < TSTEPS; ++t) {
        // 64B contiguous per lane; 16 lanes -> 1KB contiguous per row segment
        const f32x4 a0 = __builtin_nontemporal_load((const f32x4*)(Ap + 0));
        const f32x4 a1 = __builtin_nontemporal_load((const f32x4*)(Ap + 4));
        const f32x4 a2 = __builtin_nontemporal_load((const f32x4*)(Ap + 8));
        const f32x4 a3 = __builtin_nontemporal_load((const f32x4*)(Ap + 12));
        Ap += (size_t)16 * NN;

        float av[16];
#pragma unroll
        for (int j = 0; j < 4; ++j) {
            av[j] = a0[j]; av[4 + j] = a1[j]; av[8 + j] = a2[j]; av[12 + j] = a3[j];
        }

        float n0 = 0.f, n1 = 0.f, n2 = 0.f;
#pragma unroll
        for (int c = 0; c < 16; ++c) {
            dg[c] += av[c];
            n0 += av[c] * qf[3 * c + 0];
            n1 += av[c] * qf[3 * c + 1];
            n2 += av[c] * qf[3 * c + 2];
        }
        // reduce across the 16-lane column group (one row per group)
#pragma unroll
        for (int s = 1; s < 16; s <<= 1) {
            n0 += __shfl_xor(n0, s, 64);
            n1 += __shfl_xor(n1, s, 64);
            n2 += __shfl_xor(n2, s, 64);
        }
        if (cq == 0) {
            const int row = row0 + t * 16;
            float* p = npbase + (size_t)row * 3;
            if (atomic_mode) {
                atomicAdd(&p[0], n0); atomicAdd(&p[1], n1); atomicAdd(&p[2], n2);
            } else {
                p[0] = n0; p[1] = n1; p[2] = n2;
            }
        }
    }

    // combine deg across the 4 row sub-slots (xor 16, 32)
#pragma unroll
    for (int s = 16; s < 64; s <<= 1) {
#pragma unroll
        for (int c = 0; c < 16; ++c) dg[c] += __shfl_xor(dg[c], s, 64);
    }
    if (rs == 0) {   // 16 lanes x 64B contiguous = 1KB per wave
        if (atomic_mode) {
            float* dp = degp + (size_t)b * NN + col;
#pragma unroll
            for (int c = 0; c < 16; ++c) atomicAdd(&dp[c], dg[c]);
        } else {
            float* dp = degp + ((size_t)(rb * 4 + w) * BB + b) * NN + col;
#pragma unroll
            for (int k = 0; k < 4; ++k) {
                f32x4 v;
                v[0] = dg[4 * k + 0]; v[1] = dg[4 * k + 1];
                v[2] = dg[4 * k + 2]; v[3] = dg[4 * k + 3];
                *(f32x4*)(dp + 4 * k) = v;
            }
        }
    }
}

// 512 blocks x 256 threads; wave qi sums strips/slabs qi::4; LDS-combine;
// wave 0 finishes the loss for its 64 rows.
__global__ __launch_bounds__(256) void k_final(const float* __restrict__ p1,
                                               const float* __restrict__ p2,
                                               const float* __restrict__ neighp,
                                               const float* __restrict__ degp,
                                               int nslab, int ncb,
                                               float* __restrict__ out) {
    __shared__ float dredN[4][64][3];
    __shared__ float dredD[4][64];
    const int lane = threadIdx.x & 63;
    const int qi   = threadIdx.x >> 6;
    const int R    = blockIdx.x * 64 + lane;   // global row in [0, BB*NN)
    const int b    = R / NN;
    const int i    = R - b * NN;

    float n0 = 0.f, n1 = 0.f, n2 = 0.f;
    for (int c = qi; c < ncb; c += 4) {
        const float* p = neighp + ((size_t)(c * BB + b) * NN + i) * 3;
        n0 += p[0]; n1 += p[1]; n2 += p[2];
    }
    dredN[qi][lane][0] = n0; dredN[qi][lane][1] = n1; dredN[qi][lane][2] = n2;

    float d0 = 0.f;
    for (int s = qi; s < nslab; s += 4)
        d0 += degp[((size_t)s * BB + b) * NN + i];
    dredD[qi][lane] = d0;
    __syncthreads();

    if (qi == 0) {
        const float deg = dredD[0][lane] + dredD[1][lane] + dredD[2][lane] + dredD[3][lane];
        const float inv = 1.0f / deg;
        const float nd0 = dredN[0][lane][0] + dredN[1][lane][0] + dredN[2][lane][0] + dredN[3][lane][0];
        const float nd1 = dredN[0][lane][1] + dredN[1][lane][1] + dredN[2][lane][1] + dredN[3][lane][1];
        const float nd2 = dredN[0][lane][2] + dredN[1][lane][2] + dredN[2][lane][2] + dredN[3][lane][2];

        const float c0 = (p2[(size_t)R * 3 + 0] - p1[(size_t)R * 3 + 0]) - nd0 * inv;
        const float c1 = (p2[(size_t)R * 3 + 1] - p1[(size_t)R * 3 + 1]) - nd1 * inv;
        const float c2 = (p2[(size_t)R * 3 + 2] - p1[(size_t)R * 3 + 2]) - nd2 * inv;
        float acc = c0 * c0 + c1 * c1 + c2 * c2;
#pragma unroll
        for (int sft = 32; sft > 0; sft >>= 1) acc += __shfl_down(acc, sft, 64);
        if (lane == 0) atomicAdd(out, acc);
    }
}

extern "C" void kernel_launch(void* const* d_in, const int* in_sizes, int n_in,
                              void* d_out, int out_size, void* d_ws, size_t ws_size,
                              hipStream_t stream) {
    const float* pred1 = (const float*)d_in[0];
    const float* pred2 = (const float*)d_in[1];
    const float* A     = (const float*)d_in[2];
    float* out = (float*)d_out;

    float* neighp = (float*)d_ws;
    float* degp   = neighp + (size_t)NCB * BB * NN * 3;

    const size_t need_partial =
        ((size_t)NCB * BB * NN * 3 + (size_t)NDSLAB * BB * NN) * sizeof(float);
    const int atomic_mode = (ws_size < need_partial) ? 1 : 0;
    const int nslab = atomic_mode ? 1 : NDSLAB;
    const int ncb   = atomic_mode ? 1 : NCB;

    const int init_grid = atomic_mode ? (BB * NN * 3 + 255) / 256 : 1;
    k_init<<<init_grid, 256, 0, stream>>>(neighp, degp, out, atomic_mode);
    k_main<<<BB * NRB * NCB, TPB, 0, stream>>>(A, pred1, pred2, neighp, degp,
                                               atomic_mode);
    k_final<<<(BB * NN) / 64, 256, 0, stream>>>(pred1, pred2, neighp, degp,
                                                nslab, ncb, out);
}

// Round 8
// 131.688 us; speedup vs baseline: 1.2556x; 1.2556x over previous
//
#include <hip/hip_runtime.h>

#define BB 8
#define NN 4096
#define TPB 256
#define NCB 32           // column strips of 128 cols
#define SC 128           // cols per strip
#define NRB 4            // row blocks
#define RR 1024          // rows per block
#define TSTEPS (RR / 16) // 64
#define NDSLAB (NRB * 4) // deg slabs: (rb, wave)

typedef float f32x4 __attribute__((ext_vector_type(4)));

// ws layout (floats):
//   q:      [BB*NN*3]          offset 0       (98304)
//   neighp: [NCB*BB*NN*3]      offset 98304   (3145728)   (atomic: [BB*NN*3])
//   degp:   [NDSLAB*BB*NN]     offset 3244032 (524288)    (atomic: [BB*NN])
// partial-mode total ~14.4 MB

__global__ __launch_bounds__(256) void k_init(const float* __restrict__ p1,
                                              const float* __restrict__ p2,
                                              float* __restrict__ q,
                                              float* __restrict__ neighp,
                                              float* __restrict__ degp,
                                              float* __restrict__ out,
                                              int atomic_mode) {
    int i = blockIdx.x * 256 + threadIdx.x;
    if (i < BB * NN * 3) q[i] = p2[i] - p1[i];
    if (atomic_mode) {
        if (i < BB * NN * 3) neighp[i] = 0.0f;
        if (i < BB * NN) degp[i] = 0.0f;
    }
    if (i == 0) out[0] = 0.0f;
}

__global__ __launch_bounds__(TPB, 4) void k_main(const float* __restrict__ A,
                                                 const float* __restrict__ q,
                                                 float* __restrict__ neighp,
                                                 float* __restrict__ degp,
                                                 int atomic_mode) {
    const int lane = threadIdx.x & 63;
    const int w    = threadIdx.x >> 6;   // wave 0..3
    const int rs   = lane >> 4;          // row sub-slot 0..3
    const int cq   = lane & 15;          // col-octet 0..15

    int bid = blockIdx.x;
    const int cb = bid & (NCB - 1); bid >>= 5;
    const int rb = bid & (NRB - 1); bid >>= 2;
    const int b  = bid;                  // 0..7

    const int col  = cb * SC + cq * 8;   // lane's 8 fixed columns
    const int row0 = rb * RR + w * 4 + rs;

    // q for the 8 fixed columns: 24 floats, loaded once
    const float* qp = q + (size_t)b * NN * 3 + (size_t)col * 3;
    const float4 v0 = *(const float4*)(qp + 0);
    const float4 v1 = *(const float4*)(qp + 4);
    const float4 v2 = *(const float4*)(qp + 8);
    const float4 v3 = *(const float4*)(qp + 12);
    const float4 v4 = *(const float4*)(qp + 16);
    const float4 v5 = *(const float4*)(qp + 20);
    // c0=(v0.x,v0.y,v0.z) c1=(v0.w,v1.x,v1.y) c2=(v1.z,v1.w,v2.x) c3=(v2.y,v2.z,v2.w)
    // c4=(v3.x,v3.y,v3.z) c5=(v3.w,v4.x,v4.y) c6=(v4.z,v4.w,v5.x) c7=(v5.y,v5.z,v5.w)

    const float* Ap = A + (size_t)b * NN * NN + (size_t)row0 * NN + col;

    float4 dgA = make_float4(0.f, 0.f, 0.f, 0.f);
    float4 dgB = make_float4(0.f, 0.f, 0.f, 0.f);

    float* npbase = atomic_mode ? (neighp + (size_t)b * NN * 3)
                                : (neighp + (size_t)(cb * BB + b) * NN * 3);

#pragma unroll 2
    for (int t = 0; t < TSTEPS; ++t) {
        // ONLY change vs R6: non-temporal (evict-first) loads for the A stream
        const f32x4 a1v = __builtin_nontemporal_load((const f32x4*)(Ap));
        const f32x4 a2v = __builtin_nontemporal_load((const f32x4*)(Ap + 4));
        Ap += (size_t)16 * NN;
        const float4 a1 = make_float4(a1v[0], a1v[1], a1v[2], a1v[3]);
        const float4 a2 = make_float4(a2v[0], a2v[1], a2v[2], a2v[3]);

        dgA.x += a1.x; dgA.y += a1.y; dgA.z += a1.z; dgA.w += a1.w;
        dgB.x += a2.x; dgB.y += a2.y; dgB.z += a2.z; dgB.w += a2.w;

        float n0 = a1.x * v0.x + a1.y * v0.w + a1.z * v1.z + a1.w * v2.y +
                   a2.x * v3.x + a2.y * v3.w + a2.z * v4.z + a2.w * v5.y;
        float n1 = a1.x * v0.y + a1.y * v1.x + a1.z * v1.w + a1.w * v2.z +
                   a2.x * v3.y + a2.y * v4.x + a2.z * v4.w + a2.w * v5.z;
        float n2 = a1.x * v0.z + a1.y * v1.y + a1.z * v2.x + a1.w * v2.w +
                   a2.x * v3.z + a2.y * v4.y + a2.z * v5.x + a2.w * v5.w;

        // reduce across the 16-lane column group (one row per group)
#pragma unroll
        for (int s = 1; s < 16; s <<= 1) {
            n0 += __shfl_xor(n0, s, 64);
            n1 += __shfl_xor(n1, s, 64);
            n2 += __shfl_xor(n2, s, 64);
        }
        if (cq == 0) {
            const int row = row0 + t * 16;
            float* p = npbase + (size_t)row * 3;
            if (atomic_mode) {
                atomicAdd(&p[0], n0); atomicAdd(&p[1], n1); atomicAdd(&p[2], n2);
            } else {
                p[0] = n0; p[1] = n1; p[2] = n2;
            }
        }
    }

    // combine deg across the 4 row sub-slots (lanes l, l^16, l^32, l^48)
#pragma unroll
    for (int s = 16; s < 64; s <<= 1) {
        dgA.x += __shfl_xor(dgA.x, s, 64); dgA.y += __shfl_xor(dgA.y, s, 64);
        dgA.z += __shfl_xor(dgA.z, s, 64); dgA.w += __shfl_xor(dgA.w, s, 64);
        dgB.x += __shfl_xor(dgB.x, s, 64); dgB.y += __shfl_xor(dgB.y, s, 64);
        dgB.z += __shfl_xor(dgB.z, s, 64); dgB.w += __shfl_xor(dgB.w, s, 64);
    }
    if (rs == 0) {   // 16 lanes, contiguous 128B per wave
        if (atomic_mode) {
            float* dp = degp + (size_t)b * NN + col;
            atomicAdd(&dp[0], dgA.x); atomicAdd(&dp[1], dgA.y);
            atomicAdd(&dp[2], dgA.z); atomicAdd(&dp[3], dgA.w);
            atomicAdd(&dp[4], dgB.x); atomicAdd(&dp[5], dgB.y);
            atomicAdd(&dp[6], dgB.z); atomicAdd(&dp[7], dgB.w);
        } else {
            float* dp = degp + ((size_t)(rb * 4 + w) * BB + b) * NN + col;
            *(float4*)(dp + 0) = dgA;
            *(float4*)(dp + 4) = dgB;
        }
    }
}

// 512 blocks x 256 threads; wave qi sums strips/slabs qi::4; LDS-combine;
// wave 0 finishes the loss for its 64 rows.
__global__ __launch_bounds__(256) void k_final(const float* __restrict__ q,
                                               const float* __restrict__ neighp,
                                               const float* __restrict__ degp,
                                               int nslab, int ncb,
                                               float* __restrict__ out) {
    __shared__ float dredN[4][64][3];
    __shared__ float dredD[4][64];
    const int lane = threadIdx.x & 63;
    const int qi   = threadIdx.x >> 6;
    const int R    = blockIdx.x * 64 + lane;   // global row in [0, BB*NN)
    const int b    = R / NN;
    const int i    = R - b * NN;

    float n0 = 0.f, n1 = 0.f, n2 = 0.f;
    for (int c = qi; c < ncb; c += 4) {
        const float* p = neighp + ((size_t)(c * BB + b) * NN + i) * 3;
        n0 += p[0]; n1 += p[1]; n2 += p[2];
    }
    dredN[qi][lane][0] = n0; dredN[qi][lane][1] = n1; dredN[qi][lane][2] = n2;

    float d0 = 0.f;
    for (int s = qi; s < nslab; s += 4)
        d0 += degp[((size_t)s * BB + b) * NN + i];
    dredD[qi][lane] = d0;
    __syncthreads();

    if (qi == 0) {
        const float deg = dredD[0][lane] + dredD[1][lane] + dredD[2][lane] + dredD[3][lane];
        const float inv = 1.0f / deg;
        const float nd0 = dredN[0][lane][0] + dredN[1][lane][0] + dredN[2][lane][0] + dredN[3][lane][0];
        const float nd1 = dredN[0][lane][1] + dredN[1][lane][1] + dredN[2][lane][1] + dredN[3][lane][1];
        const float nd2 = dredN[0][lane][2] + dredN[1][lane][2] + dredN[2][lane][2] + dredN[3][lane][2];

        const float c0 = q[(size_t)R * 3 + 0] - nd0 * inv;
        const float c1 = q[(size_t)R * 3 + 1] - nd1 * inv;
        const float c2 = q[(size_t)R * 3 + 2] - nd2 * inv;
        float acc = c0 * c0 + c1 * c1 + c2 * c2;
#pragma unroll
        for (int sft = 32; sft > 0; sft >>= 1) acc += __shfl_down(acc, sft, 64);
        if (lane == 0) atomicAdd(out, acc);
    }
}

extern "C" void kernel_launch(void* const* d_in, const int* in_sizes, int n_in,
                              void* d_out, int out_size, void* d_ws, size_t ws_size,
                              hipStream_t stream) {
    const float* pred1 = (const float*)d_in[0];
    const float* pred2 = (const float*)d_in[1];
    const float* A     = (const float*)d_in[2];
    float* out = (float*)d_out;

    float* q      = (float*)d_ws;
    float* neighp = q + (size_t)BB * NN * 3;
    float* degp   = neighp + (size_t)NCB * BB * NN * 3;

    const size_t need_partial =
        ((size_t)BB * NN * 3 + (size_t)NCB * BB * NN * 3 + (size_t)NDSLAB * BB * NN) *
        sizeof(float);
    const int atomic_mode = (ws_size < need_partial) ? 1 : 0;
    const int nslab = atomic_mode ? 1 : NDSLAB;
    const int ncb   = atomic_mode ? 1 : NCB;

    k_init<<<(BB * NN * 3 + 255) / 256, 256, 0, stream>>>(pred1, pred2, q, neighp,
                                                          degp, out, atomic_mode);
    k_main<<<BB * NRB * NCB, TPB, 0, stream>>>(A, q, neighp, degp, atomic_mode);
    k_final<<<(BB * NN) / 64, 256, 0, stream>>>(q, neighp, degp, nslab, ncb, out);
}

// Round 9
// 119.907 us; speedup vs baseline: 1.3790x; 1.0983x over previous
//
#include <hip/hip_runtime.h>

#define BB 8
#define NN 4096
#define TPB 256
#define NCB 32           // column strips of 128 cols
#define SC 128           // cols per strip
#define NRB 4            // row blocks
#define RR 1024          // rows per block
#define TSTEPS (RR / 16) // 64
#define NDSLAB (NRB * 4) // deg slabs: (rb, wave)

typedef float f32x4 __attribute__((ext_vector_type(4)));

// ws layout (floats):
//   neighp: [NCB*BB*NN*3]    offset 0        (3145728)  (atomic: [BB*NN*3])
//   degp:   [NDSLAB*BB*NN]   offset 3145728  (524288)   (atomic: [BB*NN])
// partial-mode total ~14.7 MB

__global__ __launch_bounds__(256) void k_init(float* __restrict__ neighp,
                                              float* __restrict__ degp,
                                              float* __restrict__ out,
                                              int atomic_mode) {
    int i = blockIdx.x * 256 + threadIdx.x;
    if (atomic_mode) {
        if (i < BB * NN * 3) neighp[i] = 0.0f;
        if (i < BB * NN) degp[i] = 0.0f;
    }
    if (i == 0) out[0] = 0.0f;
}

__global__ __launch_bounds__(TPB, 4) void k_main(const float* __restrict__ A,
                                                 const float* __restrict__ p1,
                                                 const float* __restrict__ p2,
                                                 float* __restrict__ neighp,
                                                 float* __restrict__ degp,
                                                 int atomic_mode) {
    const int lane = threadIdx.x & 63;
    const int w    = threadIdx.x >> 6;   // wave 0..3
    const int rs   = lane >> 4;          // row sub-slot 0..3
    const int cq   = lane & 15;          // col-quad index 0..15

    int bid = blockIdx.x;
    const int cb = bid & (NCB - 1); bid >>= 5;
    const int rb = bid & (NRB - 1); bid >>= 2;
    const int b  = bid;                  // 0..7

    // split-strip layout: lane's cols = {colbase..+3} and {colbase+64..+67}
    // -> each load instruction covers a SOLID 256B segment per row
    const int colbase = cb * SC + cq * 4;
    const int row0    = rb * RR + w * 4 + rs;

    // q for the 8 fixed columns, computed in-register from preds
    const size_t qoff1 = ((size_t)b * NN + colbase) * 3;
    const size_t qoff2 = ((size_t)b * NN + colbase + 64) * 3;
    f32x4 qa0, qm0, qc0, qa1, qm1, qc1;
    {
        const f32x4 x0 = *(const f32x4*)(p1 + qoff1);
        const f32x4 x1 = *(const f32x4*)(p1 + qoff1 + 4);
        const f32x4 x2 = *(const f32x4*)(p1 + qoff1 + 8);
        const f32x4 y0 = *(const f32x4*)(p2 + qoff1);
        const f32x4 y1 = *(const f32x4*)(p2 + qoff1 + 4);
        const f32x4 y2 = *(const f32x4*)(p2 + qoff1 + 8);
        qa0 = y0 - x0; qm0 = y1 - x1; qc0 = y2 - x2;
        const f32x4 u0 = *(const f32x4*)(p1 + qoff2);
        const f32x4 u1 = *(const f32x4*)(p1 + qoff2 + 4);
        const f32x4 u2 = *(const f32x4*)(p1 + qoff2 + 8);
        const f32x4 v0 = *(const f32x4*)(p2 + qoff2);
        const f32x4 v1 = *(const f32x4*)(p2 + qoff2 + 4);
        const f32x4 v2 = *(const f32x4*)(p2 + qoff2 + 8);
        qa1 = v0 - u0; qm1 = v1 - u1; qc1 = v2 - u2;
    }
    // per quad (qa,qm,qc), cols c0..c3:
    // c0=(qa.x,qa.y,qa.z) c1=(qa.w,qm.x,qm.y) c2=(qm.z,qm.w,qc.x) c3=(qc.y,qc.z,qc.w)

    const float* Ap = A + (size_t)b * NN * NN + (size_t)row0 * NN + colbase;

    f32x4 dgA = {0.f, 0.f, 0.f, 0.f};
    f32x4 dgB = {0.f, 0.f, 0.f, 0.f};

    float* npbase = atomic_mode ? (neighp + (size_t)b * NN * 3)
                                : (neighp + (size_t)(cb * BB + b) * NN * 3);

#pragma unroll 2
    for (int t = 0; t < TSTEPS; ++t) {
        const f32x4 a1 = *(const f32x4*)(Ap);        // solid 256B/row across 16 lanes
        const f32x4 a2 = *(const f32x4*)(Ap + 64);   // next solid 256B
        Ap += (size_t)16 * NN;

        dgA += a1;
        dgB += a2;

        float n0 = a1[0] * qa0[0] + a1[1] * qa0[3] + a1[2] * qm0[2] + a1[3] * qc0[1] +
                   a2[0] * qa1[0] + a2[1] * qa1[3] + a2[2] * qm1[2] + a2[3] * qc1[1];
        float n1 = a1[0] * qa0[1] + a1[1] * qm0[0] + a1[2] * qm0[3] + a1[3] * qc0[2] +
                   a2[0] * qa1[1] + a2[1] * qm1[0] + a2[2] * qm1[3] + a2[3] * qc1[2];
        float n2 = a1[0] * qa0[2] + a1[1] * qm0[1] + a1[2] * qc0[0] + a1[3] * qc0[3] +
                   a2[0] * qa1[2] + a2[1] * qm1[1] + a2[2] * qc1[0] + a2[3] * qc1[3];

        // reduce across the 16-lane column group (one row per group)
#pragma unroll
        for (int s = 1; s < 16; s <<= 1) {
            n0 += __shfl_xor(n0, s, 64);
            n1 += __shfl_xor(n1, s, 64);
            n2 += __shfl_xor(n2, s, 64);
        }
        if (cq == 0) {
            const int row = row0 + t * 16;
            float* p = npbase + (size_t)row * 3;
            if (atomic_mode) {
                atomicAdd(&p[0], n0); atomicAdd(&p[1], n1); atomicAdd(&p[2], n2);
            } else {
                p[0] = n0; p[1] = n1; p[2] = n2;
            }
        }
    }

    // combine deg across the 4 row sub-slots (lanes l, l^16, l^32, l^48)
#pragma unroll
    for (int s = 16; s < 64; s <<= 1) {
#pragma unroll
        for (int j = 0; j < 4; ++j) {
            dgA[j] += __shfl_xor(dgA[j], s, 64);
            dgB[j] += __shfl_xor(dgB[j], s, 64);
        }
    }
    if (rs == 0) {   // 16 lanes x float4 = two solid 256B segments per wave
        if (atomic_mode) {
            float* dp = degp + (size_t)b * NN + colbase;
#pragma unroll
            for (int j = 0; j < 4; ++j) {
                atomicAdd(&dp[j], dgA[j]);
                atomicAdd(&dp[64 + j], dgB[j]);
            }
        } else {
            float* dp = degp + ((size_t)(rb * 4 + w) * BB + b) * NN + colbase;
            *(f32x4*)(dp) = dgA;
            *(f32x4*)(dp + 64) = dgB;
        }
    }
}

// 512 blocks x 256 threads; wave qi sums strips/slabs qi::4; LDS-combine;
// wave 0 finishes the loss for its 64 rows.
__global__ __launch_bounds__(256) void k_final(const float* __restrict__ p1,
                                               const float* __restrict__ p2,
                                               const float* __restrict__ neighp,
                                               const float* __restrict__ degp,
                                               int nslab, int ncb,
                                               float* __restrict__ out) {
    __shared__ float dredN[4][64][3];
    __shared__ float dredD[4][64];
    const int lane = threadIdx.x & 63;
    const int qi   = threadIdx.x >> 6;
    const int R    = blockIdx.x * 64 + lane;   // global row in [0, BB*NN)
    const int b    = R / NN;
    const int i    = R - b * NN;

    float n0 = 0.f, n1 = 0.f, n2 = 0.f;
    for (int c = qi; c < ncb; c += 4) {
        const float* p = neighp + ((size_t)(c * BB + b) * NN + i) * 3;
        n0 += p[0]; n1 += p[1]; n2 += p[2];
    }
    dredN[qi][lane][0] = n0; dredN[qi][lane][1] = n1; dredN[qi][lane][2] = n2;

    float d0 = 0.f;
    for (int s = qi; s < nslab; s += 4)
        d0 += degp[((size_t)s * BB + b) * NN + i];
    dredD[qi][lane] = d0;
    __syncthreads();

    if (qi == 0) {
        const float deg = dredD[0][lane] + dredD[1][lane] + dredD[2][lane] + dredD[3][lane];
        const float inv = 1.0f / deg;
        const float nd0 = dredN[0][lane][0] + dredN[1][lane][0] + dredN[2][lane][0] + dredN[3][lane][0];
        const float nd1 = dredN[0][lane][1] + dredN[1][lane][1] + dredN[2][lane][1] + dredN[3][lane][1];
        const float nd2 = dredN[0][lane][2] + dredN[1][lane][2] + dredN[2][lane][2] + dredN[3][lane][2];

        const float c0 = (p2[(size_t)R * 3 + 0] - p1[(size_t)R * 3 + 0]) - nd0 * inv;
        const float c1 = (p2[(size_t)R * 3 + 1] - p1[(size_t)R * 3 + 1]) - nd1 * inv;
        const float c2 = (p2[(size_t)R * 3 + 2] - p1[(size_t)R * 3 + 2]) - nd2 * inv;
        float acc = c0 * c0 + c1 * c1 + c2 * c2;
#pragma unroll
        for (int sft = 32; sft > 0; sft >>= 1) acc += __shfl_down(acc, sft, 64);
        if (lane == 0) atomicAdd(out, acc);
    }
}

extern "C" void kernel_launch(void* const* d_in, const int* in_sizes, int n_in,
                              void* d_out, int out_size, void* d_ws, size_t ws_size,
                              hipStream_t stream) {
    const float* pred1 = (const float*)d_in[0];
    const float* pred2 = (const float*)d_in[1];
    const float* A     = (const float*)d_in[2];
    float* out = (float*)d_out;

    float* neighp = (float*)d_ws;
    float* degp   = neighp + (size_t)NCB * BB * NN * 3;

    const size_t need_partial =
        ((size_t)NCB * BB * NN * 3 + (size_t)NDSLAB * BB * NN) * sizeof(float);
    const int atomic_mode = (ws_size < need_partial) ? 1 : 0;
    const int nslab = atomic_mode ? 1 : NDSLAB;
    const int ncb   = atomic_mode ? 1 : NCB;

    const int init_grid = atomic_mode ? (BB * NN * 3 + 255) / 256 : 1;
    k_init<<<init_grid, 256, 0, stream>>>(neighp, degp, out, atomic_mode);
    k_main<<<BB * NRB * NCB, TPB, 0, stream>>>(A, pred1, pred2, neighp, degp,
                                               atomic_mode);
    k_final<<<(BB * NN) / 64, 256, 0, stream>>>(pred1, pred2, neighp, degp,
                                                nslab, ncb, out);
}